// Round 3
// baseline (202.567 us; speedup 1.0000x reference)
//
#include <hip/hip_runtime.h>

// VectorQuantizer via f16-split-3 MFMA (Markidis fp32 emulation):
//   x = hi + lo*2^-11,  hi = f16(x), lo = f16((x-hi)*2048)
//   dot = [hi.hi] + ([hi.lo] + [lo.hi]) * 2^-11
// argmin_k ||z_hat - w_hat_k|| == argmax_k <z, w_hat_k>  -> only codebook normalized.
//
// R3: LDS in MFMA-fragment order + global_load_lds(16B) staging.
//   unit (blk,ksub) = 16 rows x 32 k, stored as [quad][l15][8 f16] = lane*16B
//   -> one wave-DMA fills one unit; one ds_read_b128 at lane*16B IS the frag.
//   Conflict-free LDS by construction; no staging VALU/LDS-writes.

typedef _Float16 half8 __attribute__((ext_vector_type(8)));
typedef float floatx4 __attribute__((ext_vector_type(4)));

#define C_DIM 256
#define K_CODES 1024
#define HW 1024
#define NPIX 32768
#define LO_SCALE 2048.0f
#define LO_INV   (1.0f/2048.0f)

#define GLOAD_LDS16(g, l) __builtin_amdgcn_global_load_lds(                    \
    (const __attribute__((address_space(1))) unsigned int*)(g),                \
    (__attribute__((address_space(3))) unsigned int*)(l), 16, 0, 0)

// ---------------- kernel 1: normalize codebook + f16 split ------------------
__global__ __launch_bounds__(256) void vq_norm_w(const float* __restrict__ w,
                                                 float* __restrict__ w_n,
                                                 _Float16* __restrict__ wh,
                                                 _Float16* __restrict__ wl) {
    const int row = blockIdx.x;        // 0..1023
    const int t   = threadIdx.x;       // 0..255
    float x = w[row * C_DIM + t];
    float s = x * x;
    #pragma unroll
    for (int off = 32; off > 0; off >>= 1) s += __shfl_down(s, off, 64);
    __shared__ float wsum[4];
    if ((t & 63) == 0) wsum[t >> 6] = s;
    __syncthreads();
    float tot = wsum[0] + wsum[1] + wsum[2] + wsum[3];
    float inv = 1.0f / fmaxf(sqrtf(tot), 1e-12f);
    float y = x * inv;
    w_n[row * C_DIM + t] = y;
    _Float16 hi = (_Float16)y;
    wh[row * C_DIM + t] = hi;
    wl[row * C_DIM + t] = (_Float16)((y - (float)hi) * LO_SCALE);
}

// ---------------- kernel 2: transpose + f16-split z -------------------------
// z [32][256][1024] -> zh/zl [32768 pixels][256 c]
__global__ __launch_bounds__(256) void vq_split_z(const float* __restrict__ z,
                                                  _Float16* __restrict__ zh,
                                                  _Float16* __restrict__ zl) {
    __shared__ float tile[64][65];
    const int t  = threadIdx.x;
    const int pt = blockIdx.x;         // 16 pixel tiles (of 64)
    const int ct = blockIdx.y;         // 4 channel tiles (of 64)
    const int b  = blockIdx.z;         // 32 batches
    const float* zb = z + ((size_t)b * C_DIM + ct * 64) * HW + pt * 64;
    const int rr = t >> 4, pp = (t & 15) * 4;
    #pragma unroll
    for (int pass = 0; pass < 4; pass++) {
        float4 v = *(const float4*)(zb + (size_t)(pass * 16 + rr) * HW + pp);
        *(float4*)&tile[pass * 16 + rr][pp] = v;
    }
    __syncthreads();
    const int pl = t >> 2;
    const size_t pix = (size_t)b * HW + pt * 64 + pl;
    #pragma unroll
    for (int pass = 0; pass < 2; pass++) {
        const int c0 = ((t & 3) + 4 * pass) * 8;
        half8 hi, lo;
        #pragma unroll
        for (int j = 0; j < 8; j++) {
            float x = tile[c0 + j][pl];
            _Float16 h = (_Float16)x;
            hi[j] = h;
            lo[j] = (_Float16)((x - (float)h) * LO_SCALE);
        }
        *(half8*)(zh + pix * C_DIM + ct * 64 + c0) = hi;
        *(half8*)(zl + pix * C_DIM + ct * 64 + c0) = lo;
    }
}

// ---------------- kernel 3: MFMA GEMM + fused argmax ------------------------
// grid (256 m-tiles, 8 n-tiles), 256 thr = 4 waves in 2x2; wave tile 64x64.
// BK = 64 (2 ksub per kt), 4 kt iterations.
__global__ __launch_bounds__(256, 2) void vq_gemm(
        const _Float16* __restrict__ zh, const _Float16* __restrict__ zl,
        const _Float16* __restrict__ wh, const _Float16* __restrict__ wl,
        float* __restrict__ cand_val, int* __restrict__ cand_idx) {
    // plane p: 0=Ah 1=Al 2=Bh 3=Bl; each [8 blk][2 ksub][512 f16] = 16 KB
    __shared__ _Float16 lds[4][8192];
    __shared__ float red_v[128][2];
    __shared__ int   red_i[128][2];

    const int tid  = threadIdx.x;
    const int lane = tid & 63, wave = tid >> 6;
    const int wm = wave >> 1, wn = wave & 1;
    const int quad = lane >> 4, l15 = lane & 15;
    const int m0 = blockIdx.x * 128, n0 = blockIdx.y * 128;

    // wave w stages plane w: per-lane global base (row = l15, col = quad*8)
    const _Float16* psrc = (wave == 0) ? zh : (wave == 1) ? zl
                         : (wave == 2) ? wh : wl;
    const int row0 = (wave < 2) ? m0 : n0;
    const _Float16* gbase = psrc + (size_t)(row0 + l15) * C_DIM + quad * 8;
    _Float16* ldsw = &lds[wave][0];

    floatx4 acc_h[4][4], acc_x[4][4];
    #pragma unroll
    for (int i = 0; i < 4; i++)
        #pragma unroll
        for (int j = 0; j < 4; j++) {
            acc_h[i][j] = (floatx4){0.f, 0.f, 0.f, 0.f};
            acc_x[i][j] = (floatx4){0.f, 0.f, 0.f, 0.f};
        }

    const int afrag = wm * 4, bfrag = wn * 4;   // frag-block bases for this wave

    for (int kt = 0; kt < 4; kt++) {
        __syncthreads();                 // prior iter's frag reads done
        const _Float16* g = gbase + kt * 64;
        #pragma unroll
        for (int u = 0; u < 16; u++) {   // unit u: blk=u>>1, ksub=u&1
            GLOAD_LDS16(g + (u >> 1) * (16 * C_DIM) + (u & 1) * 32,
                        ldsw + u * 512);
        }
        __syncthreads();                 // vmcnt(0) drain -> DMA data visible
        #pragma unroll
        for (int s = 0; s < 2; s++) {
            half8 ah[4], al[4], bh[4], bl[4];
            #pragma unroll
            for (int i = 0; i < 4; i++) {
                ah[i] = *(const half8*)&lds[0][((afrag + i) * 2 + s) * 512 + lane * 8];
                al[i] = *(const half8*)&lds[1][((afrag + i) * 2 + s) * 512 + lane * 8];
                bh[i] = *(const half8*)&lds[2][((bfrag + i) * 2 + s) * 512 + lane * 8];
                bl[i] = *(const half8*)&lds[3][((bfrag + i) * 2 + s) * 512 + lane * 8];
            }
            #pragma unroll
            for (int mi = 0; mi < 4; mi++)
                #pragma unroll
                for (int ni = 0; ni < 4; ni++) {
                    acc_h[mi][ni] = __builtin_amdgcn_mfma_f32_16x16x32_f16(ah[mi], bh[ni], acc_h[mi][ni], 0, 0, 0);
                    acc_x[mi][ni] = __builtin_amdgcn_mfma_f32_16x16x32_f16(ah[mi], bl[ni], acc_x[mi][ni], 0, 0, 0);
                    acc_x[mi][ni] = __builtin_amdgcn_mfma_f32_16x16x32_f16(al[mi], bh[ni], acc_x[mi][ni], 0, 0, 0);
                }
        }
    }

    // epilogue: combine hi/lo, per-lane best over ni, shfl-reduce over quad's 16 lanes
    #pragma unroll
    for (int mi = 0; mi < 4; mi++) {
        #pragma unroll
        for (int r = 0; r < 4; r++) {
            float bv = -__builtin_inff();
            int   bi = 0x7fffffff;
            #pragma unroll
            for (int ni = 0; ni < 4; ni++) {
                float v = acc_h[mi][ni][r] + acc_x[mi][ni][r] * LO_INV;
                int  ci = n0 + wn * 64 + ni * 16 + l15;
                if (v > bv || (v == bv && ci < bi)) { bv = v; bi = ci; }
            }
            #pragma unroll
            for (int mk = 8; mk; mk >>= 1) {
                float ov = __shfl_xor(bv, mk, 16);
                int   oi = __shfl_xor(bi, mk, 16);
                if (ov > bv || (ov == bv && oi < bi)) { bv = ov; bi = oi; }
            }
            if (l15 == 0) {
                int row = wm * 64 + mi * 16 + quad * 4 + r;  // C/D: row=(lane>>4)*4+reg
                red_v[row][wn] = bv;
                red_i[row][wn] = bi;
            }
        }
    }
    __syncthreads();
    if (tid < 128) {
        float bv = red_v[tid][0]; int bi = red_i[tid][0];
        float v2 = red_v[tid][1]; int i2 = red_i[tid][1];
        if (v2 > bv || (v2 == bv && i2 < bi)) { bv = v2; bi = i2; }
        const int pix = m0 + tid;
        cand_val[(size_t)pix * 8 + blockIdx.y] = bv;
        cand_idx[(size_t)pix * 8 + blockIdx.y] = bi;
    }
}

// ---------------- kernel 4: reduce 8 candidates + gather --------------------
__global__ __launch_bounds__(256) void vq_finalize(
        const float* __restrict__ cand_val,
        const int*   __restrict__ cand_idx,
        const float* __restrict__ w_n,
        float* __restrict__ zq,          // [32][256][1024]
        float* __restrict__ idx_out) {   // [32768] as float
    const int n = blockIdx.x * 256 + threadIdx.x;
    const size_t base = (size_t)n * 8;
    float bv = cand_val[base];
    int   bi = cand_idx[base];
    #pragma unroll
    for (int t = 1; t < 8; t++) {
        float v = cand_val[base + t];
        int   c = cand_idx[base + t];
        if (v > bv || (v == bv && c < bi)) { bv = v; bi = c; }
    }
    idx_out[n] = (float)bi;
    const int b = n >> 10;
    const int p = n & 1023;
    float* zqb = zq + (size_t)b * (C_DIM * HW) + p;
    const float* wr = w_n + (size_t)bi * C_DIM;
    #pragma unroll 4
    for (int c = 0; c < C_DIM; c += 4) {
        float4 wv = *(const float4*)(wr + c);
        zqb[(size_t)(c + 0) * HW] = wv.x;
        zqb[(size_t)(c + 1) * HW] = wv.y;
        zqb[(size_t)(c + 2) * HW] = wv.z;
        zqb[(size_t)(c + 3) * HW] = wv.w;
    }
}

// ---------------- launcher --------------------------------------------------
extern "C" void kernel_launch(void* const* d_in, const int* in_sizes, int n_in,
                              void* d_out, int out_size, void* d_ws, size_t ws_size,
                              hipStream_t stream) {
    const float* z = (const float*)d_in[0];   // 32*256*32*32
    const float* w = (const float*)d_in[1];   // 1024*256
    float* out     = (float*)d_out;           // z_q (8388608) ++ indices (32768)

    char* ws = (char*)d_ws;
    float*    w_n  = (float*)(ws);                       //  0     .. 1 MB
    _Float16* wh   = (_Float16*)(ws + (1u << 20));       //  1 MB  .. 1.5 MB
    _Float16* wl   = (_Float16*)(ws + (3u << 19));       //  1.5   .. 2 MB
    _Float16* zh   = (_Float16*)(ws + (2u << 20));       //  2 MB  .. 18 MB
    _Float16* zl   = (_Float16*)(ws + 18874368u);        // 18 MB  .. 34 MB
    float*    cval = (float*)(ws + 35651584u);           // 34 MB  .. 35 MB
    int*      cidx = (int*)(ws + 36700160u);             // 35 MB  .. 36 MB

    vq_norm_w<<<K_CODES, 256, 0, stream>>>(w, w_n, wh, wl);
    vq_split_z<<<dim3(16, 4, 32), 256, 0, stream>>>(z, zh, zl);
    vq_gemm<<<dim3(NPIX / 128, K_CODES / 128), 256, 0, stream>>>(zh, zl, wh, wl, cval, cidx);
    vq_finalize<<<NPIX / 256, 256, 0, stream>>>(cval, cidx, w_n, out, out + 8388608);
}